// Round 3
// baseline (383.163 us; speedup 1.0000x reference)
//
#include <hip/hip_runtime.h>
#include <stdint.h>

typedef unsigned short u16;
typedef unsigned int u32;

typedef __bf16 bf8 __attribute__((ext_vector_type(8)));
typedef bf8 bf8a __attribute__((may_alias));
typedef float f32x4 __attribute__((ext_vector_type(4)));
typedef uint2 uint2a __attribute__((may_alias));
typedef ushort4 ushort4a __attribute__((may_alias));
typedef float4 float4a __attribute__((may_alias));

#define MFMA_BF16(a, b, c) __builtin_amdgcn_mfma_f32_16x16x32_bf16((a), (b), (c), 0, 0, 0)

__device__ __forceinline__ u16 f2b(float x) {
  u32 u = __float_as_uint(x);
  return (u16)((u + 0x7fffu + ((u >> 16) & 1u)) >> 16);  // RNE
}
__device__ __forceinline__ u32 pack2(float a, float b) {  // two non-negative f32 -> packed bf16x2
  u32 ua = __float_as_uint(a), ub = __float_as_uint(b);
  return ((ua + 0x8000u) >> 16) | ((ub + 0x8000u) & 0xffff0000u);
}
__device__ __forceinline__ void async16(const u16* g, void* l) {
  __builtin_amdgcn_global_load_lds((const __attribute__((address_space(1))) u32*)g,
                                   (__attribute__((address_space(3))) u32*)l, 16, 0, 0);
}

// ---------------------------------------------------------------------------
// src convert: fp32 [4096][1024] -> bf16 same layout. 1 float4 per thread.
// ---------------------------------------------------------------------------
__global__ __launch_bounds__(256) void convert_src(const float* __restrict__ src,
                                                   u16* __restrict__ dst) {
  const int i = blockIdx.x * 256 + threadIdx.x;  // float4 index
  float4 v = *(const float4a*)(src + i * 4);
  ushort4 o;
  o.x = f2b(v.x); o.y = f2b(v.y); o.z = f2b(v.z); o.w = f2b(v.w);
  *(ushort4a*)(dst + i * 4) = o;
}

// ---------------------------------------------------------------------------
// Weight transpose+convert: w fp32 [K=1024][N=1024] -> wT bf16 [N][K]
// ---------------------------------------------------------------------------
__global__ __launch_bounds__(256) void transpose4(
    const float* __restrict__ w0, const float* __restrict__ w1,
    const float* __restrict__ w2, const float* __restrict__ w3,
    u16* __restrict__ t0, u16* __restrict__ t1, u16* __restrict__ t2, u16* __restrict__ t3) {
  const int z = blockIdx.z;
  const float* W = z == 0 ? w0 : z == 1 ? w1 : z == 2 ? w2 : w3;
  u16* T = z == 0 ? t0 : z == 1 ? t1 : z == 2 ? t2 : t3;
  __shared__ __align__(8) u16 tile[64][68];
  const int tid = threadIdx.x;
  const int ty = tid >> 4, tx = tid & 15;
  const int kb = blockIdx.y * 64, nb = blockIdx.x * 64;
#pragma unroll
  for (int i = 0; i < 4; ++i) {
    int lk = ty + i * 16;
    float4 v = *(const float4a*)(W + (kb + lk) * 1024 + nb + tx * 4);
    ushort4 h;
    h.x = f2b(v.x); h.y = f2b(v.y); h.z = f2b(v.z); h.w = f2b(v.w);
    *(ushort4a*)&tile[lk][tx * 4] = h;
  }
  __syncthreads();
#pragma unroll
  for (int i = 0; i < 4; ++i) {
    int ln = ty + i * 16;
    ushort4 v;
    v.x = tile[tx * 4 + 0][ln];
    v.y = tile[tx * 4 + 1][ln];
    v.z = tile[tx * 4 + 2][ln];
    v.w = tile[tx * 4 + 3][ln];
    *(ushort4a*)(T + (nb + ln) * 1024 + kb + tx * 4) = v;
  }
}

// ---------------------------------------------------------------------------
// GEMM: C[M][N] = A[M,1024] * Bt[N,1024]^T + bias[n]   (m97 structure)
// A, Bt bf16; bias fp32. block 256 = 4 waves (2x2), tile 128x128, BK=32.
// plain=1: write float Of[rm*1024+col] (final out-proj).
// plain=0: z<2 -> bf16 Q/K layout [pair][s][64]; z==2 -> bf16 V^T [pair][e][s].
// ---------------------------------------------------------------------------
__global__ __launch_bounds__(256) void gemm_bt(
    const u16* __restrict__ A,
    const u16* __restrict__ B0, const u16* __restrict__ B1, const u16* __restrict__ B2,
    const float* __restrict__ c0, const float* __restrict__ c1, const float* __restrict__ c2,
    u16* __restrict__ O0, u16* __restrict__ O1, u16* __restrict__ O2,
    float* __restrict__ Of, int plain) {
  __shared__ __align__(16) u16 sm[8192];
  u16* As = sm;
  u16* Bs = sm + 4096;
  const int tid = threadIdx.x, lane = tid & 63, w = tid >> 6;
  const int wm = w >> 1, wn = w & 1, quad = lane >> 4, l16 = lane & 15;
  const int z = blockIdx.z;
  const u16* Bt = z == 0 ? B0 : (z == 1 ? B1 : B2);
  const float* bi = z == 0 ? c0 : (z == 1 ? c1 : c2);
  u16* O = z == 0 ? O0 : (z == 1 ? O1 : O2);
  const int row0 = blockIdx.y * 128, col0 = blockIdx.x * 128;

  f32x4 acc[4][4];
#pragma unroll
  for (int i = 0; i < 4; ++i)
#pragma unroll
    for (int j = 0; j < 4; ++j) acc[i][j] = f32x4{0.f, 0.f, 0.f, 0.f};

  const int e0 = tid, e1 = tid + 256;
  const int r0 = e0 >> 2, cc0 = (e0 & 3) * 8;
  const int r1 = e1 >> 2, cc1 = (e1 & 3) * 8;
  const u32 lb0 = (u32)(w * 64) * 16;
  const u32 lb1 = (u32)(w * 64 + 256) * 16;

  for (int k0 = 0; k0 < 1024; k0 += 32) {
    __syncthreads();
    async16(A + (row0 + r0) * 1024 + k0 + cc0, (char*)As + lb0);
    async16(A + (row0 + r1) * 1024 + k0 + cc1, (char*)As + lb1);
    async16(Bt + (col0 + r0) * 1024 + k0 + cc0, (char*)Bs + lb0);
    async16(Bt + (col0 + r1) * 1024 + k0 + cc1, (char*)Bs + lb1);
    __syncthreads();
    bf8a af[4], bfr[4];
#pragma unroll
    for (int i = 0; i < 4; ++i) {
      af[i] = *(const bf8a*)(As + (wm * 64 + i * 16 + l16) * 32 + quad * 8);
      bfr[i] = *(const bf8a*)(Bs + (wn * 64 + i * 16 + l16) * 32 + quad * 8);
    }
#pragma unroll
    for (int mt = 0; mt < 4; ++mt)
#pragma unroll
      for (int nt = 0; nt < 4; ++nt) acc[mt][nt] = MFMA_BF16(af[mt], bfr[nt], acc[mt][nt]);
  }

#pragma unroll
  for (int nt = 0; nt < 4; ++nt) {
    const int col = col0 + wn * 64 + nt * 16 + l16;
    const float bcol = bi[col];
#pragma unroll
    for (int mt = 0; mt < 4; ++mt) {
#pragma unroll
      for (int r = 0; r < 4; ++r) {
        const int rm = row0 + wm * 64 + mt * 16 + quad * 4 + r;
        const float fv = acc[mt][nt][r] + bcol;
        if (plain) {
          Of[rm * 1024 + col] = fv;
        } else {
          const u16 hv = f2b(fv);
          const int s = rm >> 1, b_ = rm & 1, hh = col >> 6, e = col & 63;
          const int p = b_ * 16 + hh;
          if (z < 2) O[(p * 2048 + s) * 64 + e] = hv;  // [pair][s][64]
          else O[(p * 64 + e) * 2048 + s] = hv;        // [pair][e][s] (V^T)
        }
      }
    }
  }
}

// ---------------------------------------------------------------------------
// Flash attention. One block (4 waves) per (pair, 128-row q-tile).
// S^T = K*Q^T so s sits on lane&15: fp32 bias loads contiguous along t,
// stats reduce with shfl_xor 16/32, P round-trips LDS within-wave only.
// ---------------------------------------------------------------------------
__global__ __launch_bounds__(256) void attn_fused(
    const u16* __restrict__ Qw, const u16* __restrict__ Kw, const u16* __restrict__ Vw,
    const float* __restrict__ EB, u16* __restrict__ Ao) {
  __shared__ __align__(16) u16 Ps[128 * 136];  // [128 s][128 t], pad 8
  const int tid = threadIdx.x, lane = tid & 63, w = tid >> 6;
  const int quad = lane >> 4, l16 = lane & 15;
  const int qt = blockIdx.x, pair = blockIdx.y;
  const int bb = pair >> 4, hh = pair & 15;
  const u16* Qp = Qw + pair * (2048 * 64);
  const u16* Kp = Kw + pair * (2048 * 64);
  const u16* Vp = Vw + pair * (64 * 2048);
  const int s0 = qt * 128 + w * 32;  // wave's 32-row s strip (global)

  bf8a qf[2][2];  // B-operand (Q^T) frags: n = s, k = d
#pragma unroll
  for (int st = 0; st < 2; ++st)
#pragma unroll
    for (int ks = 0; ks < 2; ++ks)
      qf[st][ks] = *(const bf8a*)(Qp + (s0 + st * 16 + l16) * 64 + ks * 32 + quad * 8);

  f32x4 oacc[2][4];
#pragma unroll
  for (int i = 0; i < 2; ++i)
#pragma unroll
    for (int j = 0; j < 4; ++j) oacc[i][j] = f32x4{0.f, 0.f, 0.f, 0.f};
  float m_s[2] = {-1e30f, -1e30f};
  float l_s[2] = {0.f, 0.f};
  const float c1 = 0.125f * 1.44269504088896340736f;  // scale * log2(e)
  const float c2 = 1.44269504088896340736f;

  for (int kt = 0; kt < 16; ++kt) {
    // S^T = K * Q^T : D[row=t][col=s]
    f32x4 sacc[8][2];
#pragma unroll
    for (int tt = 0; tt < 8; ++tt) {
      const u16* kr = Kp + (kt * 128 + tt * 16 + l16) * 64 + quad * 8;
      bf8a k0 = *(const bf8a*)kr;
      bf8a k1 = *(const bf8a*)(kr + 32);
#pragma unroll
      for (int st = 0; st < 2; ++st) {
        f32x4 t0 = f32x4{0.f, 0.f, 0.f, 0.f};
        t0 = MFMA_BF16(k0, qf[st][0], t0);
        sacc[tt][st] = MFMA_BF16(k1, qf[st][1], t0);
      }
    }
    // z = (qk*scale + bias) * log2e; remember bf16 sign masks for the gate
    u32 sg01[8][2], sg23[8][2];
#pragma unroll
    for (int tt = 0; tt < 8; ++tt)
#pragma unroll
      for (int st = 0; st < 2; ++st) {
        const int srow = s0 + st * 16 + l16;
        const float4 b = *(const float4a*)(EB + srow * 2048 + kt * 128 + tt * 16 + quad * 4);
        sacc[tt][st][0] = sacc[tt][st][0] * c1 + b.x * c2;
        sacc[tt][st][1] = sacc[tt][st][1] * c1 + b.y * c2;
        sacc[tt][st][2] = sacc[tt][st][2] * c1 + b.z * c2;
        sacc[tt][st][3] = sacc[tt][st][3] * c1 + b.w * c2;
        sg01[tt][st] = ((__float_as_uint(b.x) >> 16) & 0x8000u) | (__float_as_uint(b.y) & 0x80000000u);
        sg23[tt][st] = ((__float_as_uint(b.z) >> 16) & 0x8000u) | (__float_as_uint(b.w) & 0x80000000u);
      }
    // row (s) max: 32 local + cross-quad shfl
    float alpha[2];
#pragma unroll
    for (int st = 0; st < 2; ++st) {
      float m = -1e30f;
#pragma unroll
      for (int tt = 0; tt < 8; ++tt) {
        m = fmaxf(m, fmaxf(fmaxf(sacc[tt][st][0], sacc[tt][st][1]),
                           fmaxf(sacc[tt][st][2], sacc[tt][st][3])));
      }
      m = fmaxf(m, __shfl_xor(m, 16));
      m = fmaxf(m, __shfl_xor(m, 32));
      const float mn = fmaxf(m_s[st], m);
      alpha[st] = exp2f(m_s[st] - mn);
      m_s[st] = mn;
    }
    // p = exp2(z - m); pack bf16 pairs with the sign gate
    u32 pd[8][2][2];
    float lsum[2] = {0.f, 0.f};
#pragma unroll
    for (int tt = 0; tt < 8; ++tt)
#pragma unroll
      for (int st = 0; st < 2; ++st) {
        const float p0 = exp2f(sacc[tt][st][0] - m_s[st]);
        const float p1 = exp2f(sacc[tt][st][1] - m_s[st]);
        const float p2 = exp2f(sacc[tt][st][2] - m_s[st]);
        const float p3 = exp2f(sacc[tt][st][3] - m_s[st]);
        lsum[st] += (p0 + p1) + (p2 + p3);
        pd[tt][st][0] = pack2(p0, p1) | sg01[tt][st];
        pd[tt][st][1] = pack2(p2, p3) | sg23[tt][st];
      }
#pragma unroll
    for (int st = 0; st < 2; ++st) {
      float s = lsum[st];
      s += __shfl_xor(s, 16);
      s += __shfl_xor(s, 32);
      l_s[st] = l_s[st] * alpha[st] + s;
    }
    // P -> LDS (C-layout write, vectorized b64; within-wave region only)
#pragma unroll
    for (int tt = 0; tt < 8; ++tt)
#pragma unroll
      for (int st = 0; st < 2; ++st) {
        const int row = w * 32 + st * 16 + l16;
        uint2 v;
        v.x = pd[tt][st][0];
        v.y = pd[tt][st][1];
        *(uint2a*)((char*)Ps + (row * 136 + tt * 16 + quad * 4) * 2) = v;
      }
    // O *= alpha (broadcast per O-row via shfl)
    float ar0[4], ar1[4];
#pragma unroll
    for (int r = 0; r < 4; ++r) {
      ar0[r] = __shfl(alpha[0], quad * 4 + r);
      ar1[r] = __shfl(alpha[1], quad * 4 + r);
    }
#pragma unroll
    for (int nt = 0; nt < 4; ++nt)
#pragma unroll
      for (int r = 0; r < 4; ++r) {
        oacc[0][nt][r] *= ar0[r];
        oacc[1][nt][r] *= ar1[r];
      }
    // PV: A = P (from LDS, A-layout b128 reads), B = V^T rows (contiguous t)
#pragma unroll
    for (int kss = 0; kss < 4; ++kss) {
      bf8a pf0 = *(const bf8a*)((char*)Ps + ((w * 32 + l16) * 136 + kss * 32 + quad * 8) * 2);
      bf8a pf1 = *(const bf8a*)((char*)Ps + ((w * 32 + 16 + l16) * 136 + kss * 32 + quad * 8) * 2);
#pragma unroll
      for (int nt = 0; nt < 4; ++nt) {
        bf8a vf = *(const bf8a*)(Vp + (nt * 16 + l16) * 2048 + kt * 128 + kss * 32 + quad * 8);
        oacc[0][nt] = MFMA_BF16(pf0, vf, oacc[0][nt]);
        oacc[1][nt] = MFMA_BF16(pf1, vf, oacc[1][nt]);
      }
    }
  }
  // epilogue: out = O / l -> Ao[(s*2+b)*1024 + h*64+e] (bf16)
#pragma unroll
  for (int mt = 0; mt < 2; ++mt) {
    float linv[4];
#pragma unroll
    for (int r = 0; r < 4; ++r) {
      const float lr = __shfl(l_s[mt], quad * 4 + r);
      linv[r] = 1.0f / lr;
    }
#pragma unroll
    for (int nt = 0; nt < 4; ++nt) {
      const int col = hh * 64 + nt * 16 + l16;
#pragma unroll
      for (int r = 0; r < 4; ++r) {
        const int srow = s0 + mt * 16 + quad * 4 + r;
        Ao[(srow * 2 + bb) * 1024 + col] = f2b(oacc[mt][nt][r] * linv[r]);
      }
    }
  }
}

// ---------------------------------------------------------------------------
extern "C" void kernel_launch(void* const* d_in, const int* in_sizes, int n_in,
                              void* d_out, int out_size, void* d_ws, size_t ws_size,
                              hipStream_t stream) {
  const float* src = (const float*)d_in[0];
  const float* eb = (const float*)d_in[1];
  const float* wq = (const float*)d_in[2];
  const float* bq = (const float*)d_in[3];
  const float* wk = (const float*)d_in[4];
  const float* bk = (const float*)d_in[5];
  const float* wv = (const float*)d_in[6];
  const float* bv = (const float*)d_in[7];
  const float* wo = (const float*)d_in[8];
  const float* bo = (const float*)d_in[9];
  u16* ws = (u16*)d_ws;
  const size_t MM = 1024 * 1024;
  u16* wqT = ws;             // bf16 [N][K]
  u16* wkT = ws + MM;
  u16* wvT = ws + 2 * MM;
  u16* woT = ws + 3 * MM;
  u16* srcB = ws + 4 * MM;   // bf16 [4096][1024]
  u16* qW = ws + 8 * MM;     // bf16 [32][2048][64]
  u16* kW = ws + 12 * MM;    // bf16 [32][2048][64]
  u16* vW = ws + 16 * MM;    // bf16 [32][64][2048] (V^T)
  u16* aO = ws + 20 * MM;    // bf16 [4096][1024]
  float* out = (float*)d_out;

  convert_src<<<dim3(4096), 256, 0, stream>>>(src, srcB);
  transpose4<<<dim3(16, 16, 4), 256, 0, stream>>>(wq, wk, wv, wo, wqT, wkT, wvT, woT);
  gemm_bt<<<dim3(8, 32, 3), 256, 0, stream>>>(srcB, wqT, wkT, wvT, bq, bk, bv,
                                              qW, kW, vW, nullptr, 0);
  attn_fused<<<dim3(16, 32), 256, 0, stream>>>(qW, kW, vW, eb, aO);
  gemm_bt<<<dim3(8, 32, 1), 256, 0, stream>>>(aO, woT, woT, woT, bo, bo, bo,
                                              nullptr, nullptr, nullptr, out, 1);
}